// Round 4
// baseline (407.557 us; speedup 1.0000x reference)
//
#include <hip/hip_runtime.h>

#define IMG 512
#define ROWS 16             // output rows per block
#define NITER 26            // ROWS + 10 input rows
#define NPLANES 24          // N*C = 8*3
#define TOTAL_PIX 6291456.0f
#define NBLOCKS (32 * 24)   // (512/ROWS) * NPLANES

// Gaussian window, sigma=1.5, K=11, normalized (validated: absmax 0.0 R1-R3).
// constexpr (not __constant__) so GW[k] with literal k folds in the frontend.
constexpr float GW[11] = {
    0.00102838f, 0.00759876f, 0.03600050f, 0.10935817f, 0.21300535f,
    0.26601172f, 0.21300535f, 0.10935817f, 0.03600050f, 0.00759876f,
    0.00102838f};

// Vertical 11-tap conv for one column: x0..x10,y0..y10 -> 5 sums.
__device__ __forceinline__ void vcol(
    float x0, float x1, float x2, float x3, float x4, float x5, float x6,
    float x7, float x8, float x9, float x10,
    float y0, float y1, float y2, float y3, float y4, float y5, float y6,
    float y7, float y8, float y9, float y10,
    float& Vx, float& Vy, float& Vxx, float& Vyy, float& Vxy) {
  Vx = 0.f; Vy = 0.f; Vxx = 0.f; Vyy = 0.f; Vxy = 0.f;
#define VK(K)                                            \
  {                                                      \
    const float wx = GW[K] * x##K, wy = GW[K] * y##K;    \
    Vx += wx;                                            \
    Vy += wy;                                            \
    Vxx = fmaf(wx, x##K, Vxx);                           \
    Vxy = fmaf(wx, y##K, Vxy);                           \
    Vyy = fmaf(wy, y##K, Vyy);                           \
  }
  VK(0) VK(1) VK(2) VK(3) VK(4) VK(5) VK(6) VK(7) VK(8) VK(9) VK(10)
#undef VK
}

// Horizontal 11-tap conv over packed float4 (a0,a1,b0,b1) units.
// Unit i covers cols 2(t-3+i), 2(t-3+i)+1. Outputs: cols 2t (s0*) and 2t+1 (s1*).
__device__ __forceinline__ void hconv4(
    const float4 p0, const float4 p1, const float4 p2, const float4 p3,
    const float4 p4, const float4 p5, const float4 p6,
    float& s0a, float& s1a, float& s0b, float& s1b) {
  s0a = GW[0] * p0.y;
  s0a = fmaf(GW[1], p1.x, s0a); s0a = fmaf(GW[2], p1.y, s0a);
  s0a = fmaf(GW[3], p2.x, s0a); s0a = fmaf(GW[4], p2.y, s0a);
  s0a = fmaf(GW[5], p3.x, s0a); s0a = fmaf(GW[6], p3.y, s0a);
  s0a = fmaf(GW[7], p4.x, s0a); s0a = fmaf(GW[8], p4.y, s0a);
  s0a = fmaf(GW[9], p5.x, s0a); s0a = fmaf(GW[10], p5.y, s0a);
  s1a = GW[0] * p1.x;
  s1a = fmaf(GW[1], p1.y, s1a); s1a = fmaf(GW[2], p2.x, s1a);
  s1a = fmaf(GW[3], p2.y, s1a); s1a = fmaf(GW[4], p3.x, s1a);
  s1a = fmaf(GW[5], p3.y, s1a); s1a = fmaf(GW[6], p4.x, s1a);
  s1a = fmaf(GW[7], p4.y, s1a); s1a = fmaf(GW[8], p5.x, s1a);
  s1a = fmaf(GW[9], p5.y, s1a); s1a = fmaf(GW[10], p6.x, s1a);
  s0b = GW[0] * p0.w;
  s0b = fmaf(GW[1], p1.z, s0b); s0b = fmaf(GW[2], p1.w, s0b);
  s0b = fmaf(GW[3], p2.z, s0b); s0b = fmaf(GW[4], p2.w, s0b);
  s0b = fmaf(GW[5], p3.z, s0b); s0b = fmaf(GW[6], p3.w, s0b);
  s0b = fmaf(GW[7], p4.z, s0b); s0b = fmaf(GW[8], p4.w, s0b);
  s0b = fmaf(GW[9], p5.z, s0b); s0b = fmaf(GW[10], p5.w, s0b);
  s1b = GW[0] * p1.z;
  s1b = fmaf(GW[1], p1.w, s1b); s1b = fmaf(GW[2], p2.z, s1b);
  s1b = fmaf(GW[3], p2.w, s1b); s1b = fmaf(GW[4], p3.z, s1b);
  s1b = fmaf(GW[5], p3.w, s1b); s1b = fmaf(GW[6], p4.z, s1b);
  s1b = fmaf(GW[7], p4.w, s1b); s1b = fmaf(GW[8], p5.z, s1b);
  s1b = fmaf(GW[9], p5.w, s1b); s1b = fmaf(GW[10], p6.z, s1b);
}

__device__ __forceinline__ void hconv2(
    const float2 q0, const float2 q1, const float2 q2, const float2 q3,
    const float2 q4, const float2 q5, const float2 q6, float& s0, float& s1) {
  s0 = GW[0] * q0.y;
  s0 = fmaf(GW[1], q1.x, s0); s0 = fmaf(GW[2], q1.y, s0);
  s0 = fmaf(GW[3], q2.x, s0); s0 = fmaf(GW[4], q2.y, s0);
  s0 = fmaf(GW[5], q3.x, s0); s0 = fmaf(GW[6], q3.y, s0);
  s0 = fmaf(GW[7], q4.x, s0); s0 = fmaf(GW[8], q4.y, s0);
  s0 = fmaf(GW[9], q5.x, s0); s0 = fmaf(GW[10], q5.y, s0);
  s1 = GW[0] * q1.x;
  s1 = fmaf(GW[1], q1.y, s1); s1 = fmaf(GW[2], q2.x, s1);
  s1 = fmaf(GW[3], q2.y, s1); s1 = fmaf(GW[4], q3.x, s1);
  s1 = fmaf(GW[5], q3.y, s1); s1 = fmaf(GW[6], q4.x, s1);
  s1 = fmaf(GW[7], q4.y, s1); s1 = fmaf(GW[8], q5.x, s1);
  s1 = fmaf(GW[9], q5.y, s1); s1 = fmaf(GW[10], q6.x, s1);
}

// rows J..J+10, row J+k lives in slot (J+k)%11 — all frontend constants
#define ROTA(A, J)                                                          \
  A[((J) + 0) % 11], A[((J) + 1) % 11], A[((J) + 2) % 11],                  \
  A[((J) + 3) % 11], A[((J) + 4) % 11], A[((J) + 5) % 11],                  \
  A[((J) + 6) % 11], A[((J) + 7) % 11], A[((J) + 8) % 11],                  \
  A[((J) + 9) % 11], A[((J) + 10) % 11]

extern "C" __global__ __launch_bounds__(256, 4) void ssim_structure_kernel(
    const float* __restrict__ x, const float* __restrict__ y,
    float* __restrict__ partial) {
  const int tid = threadIdx.x;
  const int chunk = blockIdx.x;  // 0..31 (row chunk)
  const int plane = blockIdx.y;  // 0..23
  const int r0 = chunk * ROWS;

  const size_t pbase = (size_t)plane * (IMG * IMG / 2);  // in float2 units
  const float2* __restrict__ xp = (const float2*)x + pbase;
  const float2* __restrict__ yp = (const float2*)y + pbase;

  // Packed horizontal staging, double-buffered. Unit u=3+lu, lu in [-3,258]
  // covering cols 2lu,2lu+1; pads (lu<0, lu>255) stay zero = image-edge zeros.
  __shared__ float4 b01[2][264];  // (Vx0,Vx1,Vy0,Vy1)
  __shared__ float4 b23[2][264];  // (Vxx0,Vxx1,Vyy0,Vyy1)
  __shared__ float2 b4[2][264];   // (Vxy0,Vxy1)
  for (int j = tid; j < 528; j += 256) {
    ((float4*)b01)[j] = make_float4(0.f, 0.f, 0.f, 0.f);
    ((float4*)b23)[j] = make_float4(0.f, 0.f, 0.f, 0.f);
    ((float2*)b4)[j] = make_float2(0.f, 0.f);
  }
  __syncthreads();

  // 11-row circular history for this thread's 2 columns.
  // EVERY index below is a frontend constant -> guaranteed SROA promotion.
  float bx0[11], bx1[11], by0[11], by1[11];
  float acc = 0.0f;

  auto loadrow = [&](int i, float2& ox, float2& oy) {
    const int ir = r0 - 5 + i;
    if (i < NITER && ir >= 0 && ir < IMG) {
      const size_t off = (size_t)ir * (IMG / 2) + tid;
      ox = xp[off];
      oy = yp[off];
    } else {
      ox = make_float2(0.f, 0.f);
      oy = make_float2(0.f, 0.f);
    }
  };

#define LOADP(I)                                             \
  {                                                          \
    float2 vx, vy;                                           \
    loadrow(I, vx, vy);                                      \
    bx0[I] = vx.x; bx1[I] = vx.y;                            \
    by0[I] = vy.x; by1[I] = vy.y;                            \
  }
  LOADP(0) LOADP(1) LOADP(2) LOADP(3) LOADP(4)
  LOADP(5) LOADP(6) LOADP(7) LOADP(8) LOADP(9)
#undef LOADP
  float2 px, py;
  loadrow(10, px, py);

#define STEP(J)                                                               \
  {                                                                           \
    bx0[(10 + (J)) % 11] = px.x; bx1[(10 + (J)) % 11] = px.y;                 \
    by0[(10 + (J)) % 11] = py.x; by1[(10 + (J)) % 11] = py.y;                 \
    loadrow(11 + (J), px, py);                                                \
    float Vx0, Vy0, Vxx0, Vyy0, Vxy0, Vx1, Vy1, Vxx1, Vyy1, Vxy1;            \
    vcol(ROTA(bx0, J), ROTA(by0, J), Vx0, Vy0, Vxx0, Vyy0, Vxy0);             \
    vcol(ROTA(bx1, J), ROTA(by1, J), Vx1, Vy1, Vxx1, Vyy1, Vxy1);             \
    const int sel = (J) & 1;                                                  \
    b01[sel][3 + tid] = make_float4(Vx0, Vx1, Vy0, Vy1);                      \
    b23[sel][3 + tid] = make_float4(Vxx0, Vxx1, Vyy0, Vyy1);                  \
    b4[sel][3 + tid] = make_float2(Vxy0, Vxy1);                               \
    __syncthreads();                                                          \
    float Sx0, Sx1, Sy0, Sy1, Sxx0, Sxx1, Syy0, Syy1, Sxy0, Sxy1;            \
    hconv4(b01[sel][tid], b01[sel][tid + 1], b01[sel][tid + 2],               \
           b01[sel][tid + 3], b01[sel][tid + 4], b01[sel][tid + 5],           \
           b01[sel][tid + 6], Sx0, Sx1, Sy0, Sy1);                            \
    hconv4(b23[sel][tid], b23[sel][tid + 1], b23[sel][tid + 2],               \
           b23[sel][tid + 3], b23[sel][tid + 4], b23[sel][tid + 5],           \
           b23[sel][tid + 6], Sxx0, Sxx1, Syy0, Syy1);                        \
    hconv2(b4[sel][tid], b4[sel][tid + 1], b4[sel][tid + 2],                  \
           b4[sel][tid + 3], b4[sel][tid + 4], b4[sel][tid + 5],              \
           b4[sel][tid + 6], Sxy0, Sxy1);                                     \
    {                                                                         \
      const float sxy = fmaf(-Sx0, Sy0, Sxy0);                                \
      const float sxx = fmaxf(fmaf(-Sx0, Sx0, Sxx0), 1e-12f);                 \
      const float syy = fmaxf(fmaf(-Sy0, Sy0, Syy0), 1e-12f);                 \
      const float den = __builtin_amdgcn_sqrtf(sxx * syy) + 1e-4f;            \
      acc += (sxy + 1e-4f) * __builtin_amdgcn_rcpf(den);                      \
    }                                                                         \
    {                                                                         \
      const float sxy = fmaf(-Sx1, Sy1, Sxy1);                                \
      const float sxx = fmaxf(fmaf(-Sx1, Sx1, Sxx1), 1e-12f);                 \
      const float syy = fmaxf(fmaf(-Sy1, Sy1, Syy1), 1e-12f);                 \
      const float den = __builtin_amdgcn_sqrtf(sxx * syy) + 1e-4f;            \
      acc += (sxy + 1e-4f) * __builtin_amdgcn_rcpf(den);                      \
    }                                                                         \
  }
  STEP(0) STEP(1) STEP(2) STEP(3) STEP(4) STEP(5) STEP(6) STEP(7)
  STEP(8) STEP(9) STEP(10) STEP(11) STEP(12) STEP(13) STEP(14) STEP(15)
#undef STEP

  // ---- block reduction: wave shuffle then cross-wave LDS ----
#pragma unroll
  for (int off = 32; off > 0; off >>= 1) acc += __shfl_down(acc, off, 64);
  __shared__ float wsum[4];
  if ((tid & 63) == 0) wsum[tid >> 6] = acc;
  __syncthreads();
  if (tid == 0) {
    partial[blockIdx.y * 32 + blockIdx.x] =
        wsum[0] + wsum[1] + wsum[2] + wsum[3];
  }
}

extern "C" __global__ void ssim_finalize_kernel(const float* __restrict__ partial,
                                                float* __restrict__ out) {
  const int tid = threadIdx.x;
  float s = 0.f;
  for (int j = tid; j < NBLOCKS; j += 256) s += partial[j];
#pragma unroll
  for (int off = 32; off > 0; off >>= 1) s += __shfl_down(s, off, 64);
  __shared__ float wsum[4];
  if ((tid & 63) == 0) wsum[tid >> 6] = s;
  __syncthreads();
  if (tid == 0) {
    out[0] = 1.0f - (wsum[0] + wsum[1] + wsum[2] + wsum[3]) * (1.0f / TOTAL_PIX);
  }
}

extern "C" void kernel_launch(void* const* d_in, const int* in_sizes, int n_in,
                              void* d_out, int out_size, void* d_ws,
                              size_t ws_size, hipStream_t stream) {
  const float* x = (const float*)d_in[0];
  const float* y = (const float*)d_in[1];
  float* out = (float*)d_out;
  float* partial = (float*)d_ws;  // 768 floats, fully overwritten every call

  dim3 grid(IMG / ROWS, NPLANES, 1);  // 32 x 24 = 768 blocks
  ssim_structure_kernel<<<grid, 256, 0, stream>>>(x, y, partial);
  ssim_finalize_kernel<<<1, 256, 0, stream>>>(partial, out);
}

// Round 5
// 282.736 us; speedup vs baseline: 1.4415x; 1.4415x over previous
//
#include <hip/hip_runtime.h>

#define IMG 512
#define ROWS 16             // output rows per block
#define NITER 26            // ROWS + 10 input rows
#define NPLANES 24          // N*C = 8*3
#define TOTAL_PIX 6291456.0f
#define NBLOCKS (32 * 24)   // (512/ROWS) * NPLANES

// Gaussian window, sigma=1.5, K=11, normalized (validated: absmax 0.0 R1-R4).
constexpr float GW[11] = {
    0.00102838f, 0.00759876f, 0.03600050f, 0.10935817f, 0.21300535f,
    0.26601172f, 0.21300535f, 0.10935817f, 0.03600050f, 0.00759876f,
    0.00102838f};

struct V5 { float x, y, xx, yy, xy; };
struct H4 { float s0a, s1a, s0b, s1b; };
struct H2 { float s0, s1; };

// Vertical 11-tap conv for one column. All by-value, returns by value —
// nothing address-taken, nothing for SROA to fumble.
__device__ __forceinline__ V5 vcol(
    float x0, float x1, float x2, float x3, float x4, float x5, float x6,
    float x7, float x8, float x9, float x10,
    float y0, float y1, float y2, float y3, float y4, float y5, float y6,
    float y7, float y8, float y9, float y10) {
  float Vx = 0.f, Vy = 0.f, Vxx = 0.f, Vyy = 0.f, Vxy = 0.f;
#define VK(K)                                            \
  {                                                      \
    const float wx = GW[K] * x##K, wy = GW[K] * y##K;    \
    Vx += wx;                                            \
    Vy += wy;                                            \
    Vxx = fmaf(wx, x##K, Vxx);                           \
    Vxy = fmaf(wx, y##K, Vxy);                           \
    Vyy = fmaf(wy, y##K, Vyy);                           \
  }
  VK(0) VK(1) VK(2) VK(3) VK(4) VK(5) VK(6) VK(7) VK(8) VK(9) VK(10)
#undef VK
  return {Vx, Vy, Vxx, Vyy, Vxy};
}

// Horizontal 11-tap conv over packed float4 (a0,a1,b0,b1) units.
// Unit u=tid+i covers cols 2(tid-3+i),+1. s0*: out col 2t, s1*: out col 2t+1.
__device__ __forceinline__ H4 hconv4(
    const float4 p0, const float4 p1, const float4 p2, const float4 p3,
    const float4 p4, const float4 p5, const float4 p6) {
  float s0a = GW[0] * p0.y;
  s0a = fmaf(GW[1], p1.x, s0a); s0a = fmaf(GW[2], p1.y, s0a);
  s0a = fmaf(GW[3], p2.x, s0a); s0a = fmaf(GW[4], p2.y, s0a);
  s0a = fmaf(GW[5], p3.x, s0a); s0a = fmaf(GW[6], p3.y, s0a);
  s0a = fmaf(GW[7], p4.x, s0a); s0a = fmaf(GW[8], p4.y, s0a);
  s0a = fmaf(GW[9], p5.x, s0a); s0a = fmaf(GW[10], p5.y, s0a);
  float s1a = GW[0] * p1.x;
  s1a = fmaf(GW[1], p1.y, s1a); s1a = fmaf(GW[2], p2.x, s1a);
  s1a = fmaf(GW[3], p2.y, s1a); s1a = fmaf(GW[4], p3.x, s1a);
  s1a = fmaf(GW[5], p3.y, s1a); s1a = fmaf(GW[6], p4.x, s1a);
  s1a = fmaf(GW[7], p4.y, s1a); s1a = fmaf(GW[8], p5.x, s1a);
  s1a = fmaf(GW[9], p5.y, s1a); s1a = fmaf(GW[10], p6.x, s1a);
  float s0b = GW[0] * p0.w;
  s0b = fmaf(GW[1], p1.z, s0b); s0b = fmaf(GW[2], p1.w, s0b);
  s0b = fmaf(GW[3], p2.z, s0b); s0b = fmaf(GW[4], p2.w, s0b);
  s0b = fmaf(GW[5], p3.z, s0b); s0b = fmaf(GW[6], p3.w, s0b);
  s0b = fmaf(GW[7], p4.z, s0b); s0b = fmaf(GW[8], p4.w, s0b);
  s0b = fmaf(GW[9], p5.z, s0b); s0b = fmaf(GW[10], p5.w, s0b);
  float s1b = GW[0] * p1.z;
  s1b = fmaf(GW[1], p1.w, s1b); s1b = fmaf(GW[2], p2.z, s1b);
  s1b = fmaf(GW[3], p2.w, s1b); s1b = fmaf(GW[4], p3.z, s1b);
  s1b = fmaf(GW[5], p3.w, s1b); s1b = fmaf(GW[6], p4.z, s1b);
  s1b = fmaf(GW[7], p4.w, s1b); s1b = fmaf(GW[8], p5.z, s1b);
  s1b = fmaf(GW[9], p5.w, s1b); s1b = fmaf(GW[10], p6.z, s1b);
  return {s0a, s1a, s0b, s1b};
}

__device__ __forceinline__ H2 hconv2(
    const float2 q0, const float2 q1, const float2 q2, const float2 q3,
    const float2 q4, const float2 q5, const float2 q6) {
  float s0 = GW[0] * q0.y;
  s0 = fmaf(GW[1], q1.x, s0); s0 = fmaf(GW[2], q1.y, s0);
  s0 = fmaf(GW[3], q2.x, s0); s0 = fmaf(GW[4], q2.y, s0);
  s0 = fmaf(GW[5], q3.x, s0); s0 = fmaf(GW[6], q3.y, s0);
  s0 = fmaf(GW[7], q4.x, s0); s0 = fmaf(GW[8], q4.y, s0);
  s0 = fmaf(GW[9], q5.x, s0); s0 = fmaf(GW[10], q5.y, s0);
  float s1 = GW[0] * q1.x;
  s1 = fmaf(GW[1], q1.y, s1); s1 = fmaf(GW[2], q2.x, s1);
  s1 = fmaf(GW[3], q2.y, s1); s1 = fmaf(GW[4], q3.x, s1);
  s1 = fmaf(GW[5], q3.y, s1); s1 = fmaf(GW[6], q4.x, s1);
  s1 = fmaf(GW[7], q4.y, s1); s1 = fmaf(GW[8], q5.x, s1);
  s1 = fmaf(GW[9], q5.y, s1); s1 = fmaf(GW[10], q6.x, s1);
  return {s0, s1};
}

// 11-deep row history as NAMED SCALARS (no arrays -> cannot hit scratch).
#define HDECL(p) float p##_0, p##_1, p##_2, p##_3, p##_4, p##_5, \
                       p##_6, p##_7, p##_8, p##_9, p##_10;
#define HARGS(p) p##_0, p##_1, p##_2, p##_3, p##_4, p##_5, \
                 p##_6, p##_7, p##_8, p##_9, p##_10
// straight-line copies: pure SSA renames, coalesced to zero movs
#define HSHIFT(p)                                              \
  p##_0 = p##_1; p##_1 = p##_2; p##_2 = p##_3; p##_3 = p##_4;  \
  p##_4 = p##_5; p##_5 = p##_6; p##_6 = p##_7; p##_7 = p##_8;  \
  p##_8 = p##_9; p##_9 = p##_10;

extern "C" __global__ __launch_bounds__(256, 3) void ssim_structure_kernel(
    const float* __restrict__ x, const float* __restrict__ y,
    float* __restrict__ partial) {
  const int tid = threadIdx.x;
  const int chunk = blockIdx.x;  // 0..31 (row chunk)
  const int plane = blockIdx.y;  // 0..23
  const int r0 = chunk * ROWS;

  const size_t pbase = (size_t)plane * (IMG * IMG / 2);  // in float2 units
  const float2* __restrict__ xp = (const float2*)x + pbase;
  const float2* __restrict__ yp = (const float2*)y + pbase;

  // Packed horizontal staging, double-buffered. Unit 3+lu covers cols
  // 2lu,2lu+1; pads (lu<0, lu>255) stay zero = image-edge zero padding.
  __shared__ float4 b01[2][264];  // (Vx0,Vx1,Vy0,Vy1)
  __shared__ float4 b23[2][264];  // (Vxx0,Vxx1,Vyy0,Vyy1)
  __shared__ float2 b4[2][264];   // (Vxy0,Vxy1)
  for (int j = tid; j < 528; j += 256) {
    ((float4*)b01)[j] = make_float4(0.f, 0.f, 0.f, 0.f);
    ((float4*)b23)[j] = make_float4(0.f, 0.f, 0.f, 0.f);
    ((float2*)b4)[j] = make_float2(0.f, 0.f);
  }
  __syncthreads();

  HDECL(hx0) HDECL(hx1) HDECL(hy0) HDECL(hy1)
  float acc = 0.0f;

#define LOADROW(I, PX, PY)                                    \
  {                                                           \
    const int ir_ = r0 - 5 + (I);                             \
    if ((I) < NITER && ir_ >= 0 && ir_ < IMG) {               \
      const size_t off_ = (size_t)ir_ * (IMG / 2) + tid;      \
      PX = xp[off_];                                          \
      PY = yp[off_];                                          \
    } else {                                                  \
      PX = make_float2(0.f, 0.f);                             \
      PY = make_float2(0.f, 0.f);                             \
    }                                                         \
  }

  // ---- prologue: rows r0-5 .. r0+4 into slots 0..9 ----
#define FILL(I)                                               \
  {                                                           \
    float2 tx_, ty_;                                          \
    LOADROW(I, tx_, ty_);                                     \
    hx0_##I = tx_.x; hx1_##I = tx_.y;                         \
    hy0_##I = ty_.x; hy1_##I = ty_.y;                         \
  }
  FILL(0) FILL(1) FILL(2) FILL(3) FILL(4)
  FILL(5) FILL(6) FILL(7) FILL(8) FILL(9)
#undef FILL

  float2 px, py;
  LOADROW(10, px, py);

#define STEP(J)                                                               \
  {                                                                           \
    hx0_10 = px.x; hx1_10 = px.y; hy0_10 = py.x; hy1_10 = py.y;               \
    LOADROW((J) + 11, px, py);                                                \
    const V5 v0 = vcol(HARGS(hx0), HARGS(hy0));                               \
    const V5 v1 = vcol(HARGS(hx1), HARGS(hy1));                               \
    const int sel = (J) & 1;                                                  \
    b01[sel][3 + tid] = make_float4(v0.x, v1.x, v0.y, v1.y);                  \
    b23[sel][3 + tid] = make_float4(v0.xx, v1.xx, v0.yy, v1.yy);              \
    b4[sel][3 + tid] = make_float2(v0.xy, v1.xy);                             \
    __syncthreads();                                                          \
    const H4 hA = hconv4(b01[sel][tid], b01[sel][tid + 1], b01[sel][tid + 2], \
                         b01[sel][tid + 3], b01[sel][tid + 4],                \
                         b01[sel][tid + 5], b01[sel][tid + 6]);               \
    const H4 hB = hconv4(b23[sel][tid], b23[sel][tid + 1], b23[sel][tid + 2], \
                         b23[sel][tid + 3], b23[sel][tid + 4],                \
                         b23[sel][tid + 5], b23[sel][tid + 6]);               \
    const H2 hC = hconv2(b4[sel][tid], b4[sel][tid + 1], b4[sel][tid + 2],    \
                         b4[sel][tid + 3], b4[sel][tid + 4],                  \
                         b4[sel][tid + 5], b4[sel][tid + 6]);                 \
    {                                                                         \
      const float sxy = fmaf(-hA.s0a, hA.s0b, hC.s0);                         \
      const float sxx = fmaxf(fmaf(-hA.s0a, hA.s0a, hB.s0a), 1e-12f);         \
      const float syy = fmaxf(fmaf(-hA.s0b, hA.s0b, hB.s0b), 1e-12f);         \
      const float den = __builtin_amdgcn_sqrtf(sxx * syy) + 1e-4f;            \
      acc += (sxy + 1e-4f) * __builtin_amdgcn_rcpf(den);                      \
    }                                                                         \
    {                                                                         \
      const float sxy = fmaf(-hA.s1a, hA.s1b, hC.s1);                         \
      const float sxx = fmaxf(fmaf(-hA.s1a, hA.s1a, hB.s1a), 1e-12f);         \
      const float syy = fmaxf(fmaf(-hA.s1b, hA.s1b, hB.s1b), 1e-12f);         \
      const float den = __builtin_amdgcn_sqrtf(sxx * syy) + 1e-4f;            \
      acc += (sxy + 1e-4f) * __builtin_amdgcn_rcpf(den);                      \
    }                                                                         \
    HSHIFT(hx0) HSHIFT(hx1) HSHIFT(hy0) HSHIFT(hy1)                           \
  }
  STEP(0) STEP(1) STEP(2) STEP(3) STEP(4) STEP(5) STEP(6) STEP(7)
  STEP(8) STEP(9) STEP(10) STEP(11) STEP(12) STEP(13) STEP(14) STEP(15)
#undef STEP
#undef LOADROW

  // ---- block reduction: wave shuffle then cross-wave LDS ----
#pragma unroll
  for (int off = 32; off > 0; off >>= 1) acc += __shfl_down(acc, off, 64);
  __shared__ float wsum[4];
  if ((tid & 63) == 0) wsum[tid >> 6] = acc;
  __syncthreads();
  if (tid == 0) {
    partial[blockIdx.y * 32 + blockIdx.x] =
        wsum[0] + wsum[1] + wsum[2] + wsum[3];
  }
}

extern "C" __global__ void ssim_finalize_kernel(const float* __restrict__ partial,
                                                float* __restrict__ out) {
  const int tid = threadIdx.x;
  float s = 0.f;
  for (int j = tid; j < NBLOCKS; j += 256) s += partial[j];
#pragma unroll
  for (int off = 32; off > 0; off >>= 1) s += __shfl_down(s, off, 64);
  __shared__ float wsum[4];
  if ((tid & 63) == 0) wsum[tid >> 6] = s;
  __syncthreads();
  if (tid == 0) {
    out[0] = 1.0f - (wsum[0] + wsum[1] + wsum[2] + wsum[3]) * (1.0f / TOTAL_PIX);
  }
}

extern "C" void kernel_launch(void* const* d_in, const int* in_sizes, int n_in,
                              void* d_out, int out_size, void* d_ws,
                              size_t ws_size, hipStream_t stream) {
  const float* x = (const float*)d_in[0];
  const float* y = (const float*)d_in[1];
  float* out = (float*)d_out;
  float* partial = (float*)d_ws;  // 768 floats, fully overwritten every call

  dim3 grid(IMG / ROWS, NPLANES, 1);  // 32 x 24 = 768 blocks
  ssim_structure_kernel<<<grid, 256, 0, stream>>>(x, y, partial);
  ssim_finalize_kernel<<<1, 256, 0, stream>>>(partial, out);
}

// Round 6
// 126.886 us; speedup vs baseline: 3.2120x; 2.2283x over previous
//
#include <hip/hip_runtime.h>

#define IMG_H 512
#define IMG_W 512
#define NPLANES 24          // N*C = 8*3
#define ROWS_PER_BLK 16     // output rows per block (R1 had 32; halved for TLP)
#define STRIPW 256          // columns per block (one thread per column)
#define NITER 26            // ROWS_PER_BLK + 10 halo rows
#define TOTAL_PIX 6291456.0f // 8*3*512*512

// Gaussian window, sigma=1.5, K=11, normalized (validated: absmax 0.0 R1-R5)
__device__ __constant__ float GW[11] = {
    0.00102838f, 0.00759876f, 0.03600050f, 0.10935817f, 0.21300535f,
    0.26601172f, 0.21300535f, 0.10935817f, 0.03600050f, 0.00759876f,
    0.00102838f};

// NOTE: this is the R1 code shape, which compiled with ZERO scratch traffic
// (WRITE_SIZE 24 B, VGPR 48). The vertical-first restructures (R2-R5) all
// generated 67-534 MB of scratch round-trip regardless of how the row history
// was expressed (arrays, frontend-constant indices, named scalars). Do not
// restructure this loop; change only grid geometry / epilogue math.

extern "C" __global__ __launch_bounds__(256) void ssim_structure_kernel(
    const float* __restrict__ x, const float* __restrict__ y,
    float* __restrict__ accum) {
  const int tid = threadIdx.x;
  const int chunk = blockIdx.x;  // 0..31  (row chunk)
  const int strip = blockIdx.y;  // 0..1   (column strip)
  const int plane = blockIdx.z;  // 0..23

  const size_t pbase = (size_t)plane * IMG_H * IMG_W;
  const float* __restrict__ xp = x + pbase;
  const float* __restrict__ yp = y + pbase;
  const int cbase = strip * STRIPW;
  const int r0 = chunk * ROWS_PER_BLK;

  // double-buffered staging row: 266 needed (256 + 10 halo), pad to 272
  __shared__ float2 lrow[2][STRIPW + 16];

  // circular register buffers of horizontal sums (indices compile-time via
  // the unroll-by-11 trick below)
  float bx[11], by[11], bxx[11], byy[11], bxy[11];

  float acc = 0.0f;

  // ---- row loader (prefetch into registers) ----
  const int gc = cbase - 5 + tid;        // main element column
  const int gc2 = gc + STRIPW;           // halo element column (tid < 10)
  float2 pre_m, pre_e;

  auto loadrow = [&](int i, float2& m, float2& e) {
    const int hr = r0 - 5 + i;
    const bool rvalid = (i < NITER) & (hr >= 0) & (hr < IMG_H);
    float xv = 0.f, yv = 0.f, xe = 0.f, ye = 0.f;
    if (rvalid) {
      const int rowoff = hr * IMG_W;
      if (gc >= 0 && gc < IMG_W) {
        xv = xp[rowoff + gc];
        yv = yp[rowoff + gc];
      }
      if (tid < 10 && gc2 < IMG_W) {  // gc2 >= 0 always
        xe = xp[rowoff + gc2];
        ye = yp[rowoff + gc2];
      }
    }
    m = make_float2(xv, yv);
    e = make_float2(xe, ye);
  };

  loadrow(0, pre_m, pre_e);

  for (int ob = 0; ob < 3; ++ob) {  // 3 * 11 = 33 iterations (26 useful)
#pragma unroll
    for (int ii = 0; ii < 11; ++ii) {
      const int i = ob * 11 + ii;
      const int sel = i & 1;

      // stage prefetched row into LDS
      lrow[sel][tid] = pre_m;
      if (tid < 10) lrow[sel][STRIPW + tid] = pre_e;
      __syncthreads();

      // prefetch next row (hides global latency behind compute)
      loadrow(i + 1, pre_m, pre_e);

      // horizontal pass -> circular slot ii (== i % 11)
      if (i < NITER) {
        float tx = 0.f, ty = 0.f, txx = 0.f, tyy = 0.f, txy = 0.f;
#pragma unroll
        for (int d = 0; d < 11; ++d) {
          const float2 v = lrow[sel][tid + d];
          const float wgt = GW[d];
          const float wx = wgt * v.x;
          const float wy = wgt * v.y;
          tx += wx;
          ty += wy;
          txx = fmaf(wx, v.x, txx);
          txy = fmaf(wx, v.y, txy);
          tyy = fmaf(wy, v.y, tyy);
        }
        bx[ii] = tx;
        by[ii] = ty;
        bxx[ii] = txx;
        byy[ii] = tyy;
        bxy[ii] = txy;
      }

      // vertical pass + epilogue for output row r0 + (i - 10)
      if (i >= 10 && i < NITER) {
        float vx = 0.f, vy = 0.f, vxx = 0.f, vyy = 0.f, vxy = 0.f;
#pragma unroll
        for (int k = 0; k < 11; ++k) {
          const int s = (ii + 1 + k) % 11;  // compile-time after unroll
          const float wgt = GW[k];
          vx = fmaf(wgt, bx[s], vx);
          vy = fmaf(wgt, by[s], vy);
          vxx = fmaf(wgt, bxx[s], vxx);
          vyy = fmaf(wgt, byy[s], vyy);
          vxy = fmaf(wgt, bxy[s], vxy);
        }
        const float sxy = vxy - vx * vy;
        const float sxx = fmaxf(vxx - vx * vx, 1e-12f);
        const float syy = fmaxf(vyy - vy * vy, 1e-12f);
        const float den = __builtin_amdgcn_sqrtf(sxx * syy) + 1e-4f;
        acc += (sxy + 1e-4f) * __builtin_amdgcn_rcpf(den);
      }
    }
  }

  // ---- block reduction: wave shuffle then cross-wave LDS ----
#pragma unroll
  for (int off = 32; off > 0; off >>= 1) acc += __shfl_down(acc, off, 64);
  __shared__ float wsum[4];
  if ((tid & 63) == 0) wsum[tid >> 6] = acc;
  __syncthreads();
  if (tid == 0) {
    atomicAdd(accum, wsum[0] + wsum[1] + wsum[2] + wsum[3]);
  }
}

extern "C" __global__ void ssim_finalize_kernel(const float* __restrict__ accum,
                                                float* __restrict__ out) {
  out[0] = 1.0f - accum[0] * (1.0f / TOTAL_PIX);
}

extern "C" void kernel_launch(void* const* d_in, const int* in_sizes, int n_in,
                              void* d_out, int out_size, void* d_ws,
                              size_t ws_size, hipStream_t stream) {
  const float* x = (const float*)d_in[0];
  const float* y = (const float*)d_in[1];
  float* out = (float*)d_out;
  float* accum = (float*)d_ws;

  hipMemsetAsync(accum, 0, sizeof(float), stream);

  dim3 grid(IMG_H / ROWS_PER_BLK, IMG_W / STRIPW, NPLANES);  // 32 x 2 x 24
  ssim_structure_kernel<<<grid, 256, 0, stream>>>(x, y, accum);
  ssim_finalize_kernel<<<1, 1, 0, stream>>>(accum, out);
}